// Round 13
// baseline (127.612 us; speedup 1.0000x reference)
//
#include <hip/hip_runtime.h>
#include <math.h>

#define T_STEPS 730
#define NB      1000
#define LENF    15
#define NEARZ   1e-5f
#define TPAD    736            // per-lane row stride (floats); 730 rounded to x16B
#define NLANES  8000           // 1000 basins x 8 members

// ===========================================================================
// PASS A: serial S/G recurrence only. Per chunk (8 steps):
//   [flush prev ring: 4 dwordx4 stores] [prefetch chunk c+3: 8 loads]
//   [sched_barrier] [8 physics steps -> fill other ring half]
// Stores grouped BEFORE loads => vmcnt FIFO is [stores][loads]: the load-wait
// 3 chunks later never waits behind a younger store ack (m135: FIFO order).
// Double ring (16 regs/plane): store->overwrite distance = 1 chunk.
// ===========================================================================
#define STEPA(CURV, RJ)                                                        \
  {                                                                            \
    float pcp = (CURV).x, pet = (CURV).y;                                      \
    float W     = pcp + S;                                                     \
    float term  = fmaf(W, inv2a, pb2a);                                        \
    float disc  = fmaf(term, term, -(W * boa));                                \
    float r     = __builtin_amdgcn_sqrtf(fmaxf(disc, NEARZ));                  \
    float Y     = term - r;                                                    \
    float e     = __builtin_amdgcn_exp2f(pet * ninvbl2);                       \
    float Sn    = Y * e;                                                       \
    float avail = W - Y;                                                       \
    float Gn    = fmaf(pc, avail, G) * inv1pd;                                 \
    S = Sn; G = Gn;                                                            \
    sr[(RJ)] = Sn;                                                             \
    gr[(RJ)] = Gn;                                                             \
  }

#define PF(BUF, CI)                                                            \
  _Pragma("unroll")                                                            \
  for (int j = 0; j < 8; ++j) BUF[j] = xf[((CI) * 8 + j) * NB + b];            \
  __builtin_amdgcn_sched_barrier(0);

#define PFC(BUF, CI)                                                           \
  _Pragma("unroll")                                                            \
  for (int j = 0; j < 8; ++j) {                                                \
      int tt = (CI) * 8 + j;                                                   \
      tt = tt < T_STEPS ? tt : (T_STEPS - 1);                                  \
      BUF[j] = xf[tt * NB + b];                                                \
  }                                                                            \
  __builtin_amdgcn_sched_barrier(0);

#define FLUSH(R)                                                               \
  *(float4*)(pS)     = make_float4(sr[(R)], sr[(R)+1], sr[(R)+2], sr[(R)+3]);  \
  *(float4*)(pS + 4) = make_float4(sr[(R)+4], sr[(R)+5], sr[(R)+6], sr[(R)+7]);\
  *(float4*)(pG)     = make_float4(gr[(R)], gr[(R)+1], gr[(R)+2], gr[(R)+3]);  \
  *(float4*)(pG + 4) = make_float4(gr[(R)+4], gr[(R)+5], gr[(R)+6], gr[(R)+7]);\
  pS += 8; pG += 8;

#define CHUNK8(RFL, BUFPF, CI, BUFC, RFILL)                                    \
  { FLUSH(RFL) PF(BUFPF, CI) }                                                 \
  _Pragma("unroll")                                                            \
  for (int j = 0; j < 8; ++j) STEPA(BUFC[j], (RFILL) + j)

__global__ __launch_bounds__(64, 1) void scan_state(const float* __restrict__ x,
                                                    const float* __restrict__ raw,
                                                    float* __restrict__ snp,
                                                    float* __restrict__ gnp) {
    const int L   = threadIdx.x;
    const int gid = blockIdx.x * 64 + L;   // 0..7999 (grid=125)
    const int b   = gid >> 3;
    const int m   = gid & 7;

    // raw layout (B,34) = [a(8), b(8), c(8), d(8), ra, rb]
    const float* rp = raw + b * 34;
    float pa = rp[0 * 8 + m] * 0.9f + 0.1f;
    float pb = rp[1 * 8 + m] * 450.0f + 50.0f;
    float pc = rp[2 * 8 + m];
    float pd = rp[3 * 8 + m] * 0.89f + 0.01f;

    float inv2a   = 1.0f / (2.0f * pa);
    float pb2a    = pb * inv2a;
    float boa     = pb / pa;
    float ninvbl2 = -1.4426950408889634f / pb;   // exp(-pet/b)=exp2(pet*this)
    float inv1pd  = 1.0f / (1.0f + pd);

    float* pS = snp + (size_t)gid * TPAD;  // 16B-aligned (736*4 % 16 == 0)
    float* pG = gnp + (size_t)gid * TPAD;

    float S = 50.0f, G = 10.0f;
    float sr[16], gr[16];                  // double ring: chunk c fills (c&1)*8

    const float2* __restrict__ xf = (const float2*)x;   // (T,B) of (p,pet)

    float2 A[8], B[8], C[8], D[8];
    PF(A, 0) PF(B, 1) PF(C, 2)             // prefetch distance 3

    // chunk 0: consume A, fill ring0, prefetch 3 -> D (no flush yet)
    { PF(D, 3) }
#pragma unroll
    for (int j = 0; j < 8; ++j) STEPA(A[j], j);

    // chunks 1..84: 21 iterations x 4 chunks. Consume B,C,D,A; prefetch
    // c+3 into A,B,C,D; ring parity alternates (compile-time).
    for (int g = 0; g < 21; ++g) {
        const int c0 = 4 * g + 1;
        CHUNK8(0, A, c0 + 3, B, 8);        // chunk c0   (odd):  fill ring8
        CHUNK8(8, B, c0 + 4, C, 0);        // chunk c0+1 (even): fill ring0
        CHUNK8(0, C, c0 + 5, D, 8);        // chunk c0+2
        CHUNK8(8, D, c0 + 6, A, 0);        // chunk c0+3
    }
    // explicit chunks 85..90 (prefetch 88..90 unclamped, 91 clamped)
    CHUNK8(0, A, 88, B, 8);                // c=85
    CHUNK8(8, B, 89, C, 0);                // c=86
    CHUNK8(0, C, 90, D, 8);                // c=87
    { FLUSH(8) PFC(D, 91) }                // c=88 flush+PF (clamped)
#pragma unroll
    for (int j = 0; j < 8; ++j) STEPA(A[j], j);
    { FLUSH(0) }                           // c=89
#pragma unroll
    for (int j = 0; j < 8; ++j) STEPA(B[j], 8 + j);
    { FLUSH(8) }                           // c=90
#pragma unroll
    for (int j = 0; j < 8; ++j) STEPA(C[j], j);
    // tail: t=728,729 from clamped chunk 91 (D[0],D[1]); fill ring8[0..1]
    STEPA(D[0], 8)
    STEPA(D[1], 9)
    { FLUSH(0) }                           // chunk 90 results (t=720..727)
    *(float2*)(pS) = make_float2(sr[8], sr[9]);
    *(float2*)(pG) = make_float2(gr[8], gr[9]);
}

// ===========================================================================
// PASS B: t-parallel finalize. Block = 256 = one (t-tile, basin); grid
// (3,1000). UH weights computed ONCE per block into LDS (was per-thread:
// ~half the VALU). Reconstruct Y = Sn*exp2(+pet/b), means over m, ch3..5;
// qs/qg sums staged in LDS (tile + 14 halo); 15-tap conv -> ch0..2.
// ===========================================================================
__global__ __launch_bounds__(256) void finalize(const float* __restrict__ x,
                                                const float* __restrict__ raw,
                                                const float* __restrict__ snp,
                                                const float* __restrict__ gnp,
                                                float* __restrict__ out) {
    __shared__ float qs_sh[270], qg_sh[270], w_sh[16];

    const int b     = blockIdx.y;
    const int tbase = blockIdx.x * 256;
    const int tid   = threadIdx.x;

    const float* rp = raw + b * 34;

    // ---- UH raw weights: 15 threads, one (exp,log) each -------------------
    if (tid < LENF) {
        float ra = rp[32] * 2.9f;
        float rb = rp[33] * 6.5f;
        float aa = fmaxf(ra, 0.0f) + 0.1f;
        float th = fmaxf(rb, 0.0f) + 0.5f;
        float tk = (float)tid + 0.5f;
        w_sh[tid] = __expf((aa - 1.0f) * __logf(tk) - tk / th);
    }

    // per-member derived params (block-uniform loads -> broadcast)
    float e2s[8], omc_[8], d_[8];
#pragma unroll
    for (int m = 0; m < 8; ++m) {
        float pb = rp[8 + m] * 450.0f + 50.0f;
        e2s[m]  = 1.4426950408889634f / pb;     // Y = Sn * exp2(pet * e2s)
        omc_[m] = 1.0f - rp[16 + m];
        d_[m]   = rp[24 + m] * 0.89f + 0.01f;
    }

    const float2* __restrict__ xf = (const float2*)x;

    // ---- compute phase: 270 t-values (tile + 14-step halo) ----------------
#pragma unroll
    for (int it = 0; it < 2; ++it) {
        int idx = tid + it * 256;
        if (idx < 270) {
            int tt = tbase + idx - 14;
            float qs = 0.0f, qg = 0.0f;
            if (tt >= 0 && tt < T_STEPS) {
                float2 pc2 = xf[tt * NB + b];
                float p = pc2.x, pet = pc2.y;
                float aet = 0.0f, ssum = 0.0f, gsum = 0.0f;
                int tprev = tt > 0 ? tt - 1 : 0;
#pragma unroll
                for (int m = 0; m < 8; ++m) {
                    const float* rowS = snp + (size_t)(b * 8 + m) * TPAD;
                    const float* rowG = gnp + (size_t)(b * 8 + m) * TPAD;
                    float sn = rowS[tt];
                    float sp = tt > 0 ? rowS[tprev] : 50.0f;
                    float gn = rowG[tt];
                    float y  = sn * __builtin_amdgcn_exp2f(pet * e2s[m]);
                    float avail = (p + sp) - y;
                    qs   += omc_[m] * avail;
                    qg   += d_[m] * gn;
                    aet  += y - sn;
                    ssum += sn;
                    gsum += gn;
                }
                if (idx >= 14) {   // own tile only (halo owned by prev block)
                    float* o = out + ((size_t)tt * NB + b) * 6;
                    o[3] = aet * 0.125f;
                    o[4] = ssum * 0.125f;
                    o[5] = gsum * 0.125f;
                }
            }
            qs_sh[idx] = qs;       // zero for tt<0 (block 0 halo) / tt>=T
            qg_sh[idx] = qg;
        }
    }
    __syncthreads();

    // ---- conv phase -------------------------------------------------------
    const int t = tbase + tid;
    if (t >= T_STEPS) return;

    float sw = 0.0f;
#pragma unroll
    for (int k = 0; k < LENF; ++k) sw += w_sh[k];
    float invs = 0.125f / sw;      // UH normalization x ensemble mean
    float ys = 0.0f, yg = 0.0f;
#pragma unroll
    for (int k = 0; k < LENF; ++k) {
        float wk = w_sh[k] * invs;
        ys = fmaf(qs_sh[tid + 14 - k], wk, ys);
        yg = fmaf(qg_sh[tid + 14 - k], wk, yg);
    }
    float* o = out + ((size_t)t * NB + b) * 6;
    o[0] = ys + yg;
    o[1] = ys;
    o[2] = yg;
}

// ===========================================================================
// FALLBACK (ws too small for the 47MB state planes): R8's proven path.
// ===========================================================================
template <int CTRL>
__device__ __forceinline__ float dpp_mov(float x) {
    int xi = __builtin_bit_cast(int, x);
    int r  = __builtin_amdgcn_update_dpp(0, xi, CTRL, 0xF, 0xF, true);
    return __builtin_bit_cast(float, r);
}
__device__ __forceinline__ float sum8(float v) {
    v += dpp_mov<0xB1>(v);
    v += dpp_mov<0x4E>(v);
    v += dpp_mov<0x141>(v);
    return v;
}

#define STEPF(CURV)                                                            \
  {                                                                            \
    float pcp = (CURV).x, pet = (CURV).y;                                      \
    float W     = pcp + S;                                                     \
    float term  = fmaf(W, inv2a, pb2a);                                        \
    float disc  = fmaf(term, term, -(W * boa));                                \
    float r     = __builtin_amdgcn_sqrtf(fmaxf(disc, NEARZ));                  \
    float Y     = term - r;                                                    \
    float e     = __builtin_amdgcn_exp2f(pet * ninvbl2);                       \
    float Sn    = Y * e;                                                       \
    float AET   = Y - Sn;                                                      \
    float avail = W - Y;                                                       \
    float Qs    = omc * avail;                                                 \
    float Gn    = fmaf(pc, avail, G) * inv1pd;                                 \
    float Qg    = pd * Gn;                                                     \
    S = Sn; G = Gn;                                                            \
    float qs_s = sum8(Qs);                                                     \
    float qg_s = sum8(Qg);                                                     \
    float ae_s = sum8(AET);                                                    \
    float s_s  = sum8(Sn);                                                     \
    float g_s  = sum8(Gn);                                                     \
    float v = qs_s;                                                            \
    v = (m == 1) ? qg_s : v;                                                   \
    v = (m == 2) ? ae_s : v;                                                   \
    v = (m == 3) ? s_s  : v;                                                   \
    v = (m >= 4) ? g_s  : v;                                                   \
    *optr = v * 0.125f;                                                        \
    optr += incr;                                                              \
  }

__global__ __launch_bounds__(64, 1) void scan_fb(const float* __restrict__ x,
                                                 const float* __restrict__ raw,
                                                 float* __restrict__ out,
                                                 float* __restrict__ qs_ws,
                                                 float* __restrict__ qg_ws,
                                                 float* __restrict__ dummy) {
    const int L  = threadIdx.x;
    const int lb = L >> 3;
    const int m  = L & 7;
    const int b  = blockIdx.x * 8 + lb;

    const float* rp = raw + b * 34;
    float pa = rp[0 * 8 + m] * 0.9f + 0.1f;
    float pb = rp[1 * 8 + m] * 450.0f + 50.0f;
    float pc = rp[2 * 8 + m];
    float pd = rp[3 * 8 + m] * 0.89f + 0.01f;
    float inv2a   = 1.0f / (2.0f * pa);
    float pb2a    = pb * inv2a;
    float boa     = pb / pa;
    float ninvbl2 = -1.4426950408889634f / pb;
    float omc     = 1.0f - pc;
    float inv1pd  = 1.0f / (1.0f + pd);

    float* optr;
    long long incr;
    if      (m == 0) { optr = qs_ws + b;                      incr = NB;     }
    else if (m == 1) { optr = qg_ws + b;                      incr = NB;     }
    else if (m <= 4) { optr = out + (long long)b * 6 + m + 1; incr = NB * 6; }
    else             { optr = dummy + (blockIdx.x * 64 + L);  incr = 0;      }

    float S = 50.0f, G = 10.0f;
    const float2* __restrict__ xf = (const float2*)x;

    float2 A[10], B[10], C[10];
#pragma unroll
    for (int j = 0; j < 10; ++j) A[j] = xf[j * NB + b];
#pragma unroll
    for (int j = 0; j < 10; ++j) B[j] = xf[(10 + j) * NB + b];

    for (int cg = 0; cg < 24; ++cg) {
        const int c0 = 3 * cg;
#pragma unroll
        for (int j = 0; j < 10; ++j) C[j] = xf[((c0 + 2) * 10 + j) * NB + b];
        __builtin_amdgcn_sched_barrier(0);
#pragma unroll
        for (int j = 0; j < 10; ++j) STEPF(A[j]);
#pragma unroll
        for (int j = 0; j < 10; ++j) A[j] = xf[((c0 + 3) * 10 + j) * NB + b];
        __builtin_amdgcn_sched_barrier(0);
#pragma unroll
        for (int j = 0; j < 10; ++j) STEPF(B[j]);
#pragma unroll
        for (int j = 0; j < 10; ++j) {
            int t = (c0 + 4) * 10 + j;
            t = t < T_STEPS ? t : (T_STEPS - 1);
            B[j] = xf[t * NB + b];
        }
        __builtin_amdgcn_sched_barrier(0);
#pragma unroll
        for (int j = 0; j < 10; ++j) STEPF(C[j]);
    }
#pragma unroll
    for (int j = 0; j < 10; ++j) STEPF(A[j]);
}

__global__ __launch_bounds__(256) void uh_fb(const float* __restrict__ raw,
                                             float* __restrict__ uh) {
    int b = blockIdx.x * 256 + threadIdx.x;
    if (b >= NB) return;
    float ra = raw[b * 34 + 32] * 2.9f;
    float rb = raw[b * 34 + 33] * 6.5f;
    float aa = fmaxf(ra, 0.0f) + 0.1f;
    float th = fmaxf(rb, 0.0f) + 0.5f;
    float inv_th = 1.0f / th;
    float am1 = aa - 1.0f;
    float w[LENF];
    float s = 0.0f;
#pragma unroll
    for (int k = 0; k < LENF; ++k) {
        float t = (float)k + 0.5f;
        w[k] = __expf(am1 * __logf(t) - t * inv_th);
        s += w[k];
    }
    float invs = 1.0f / s;
#pragma unroll
    for (int k = 0; k < LENF; ++k) uh[k * NB + b] = w[k] * invs;
}

__global__ __launch_bounds__(256) void conv_fb(const float* __restrict__ qs_ws,
                                               const float* __restrict__ qg_ws,
                                               const float* __restrict__ uh,
                                               float* __restrict__ out) {
    int b = blockIdx.x * 256 + threadIdx.x;
    int t = blockIdx.y;
    if (b >= NB) return;
    float ys = 0.0f, yg = 0.0f;
    int kmax = t < (LENF - 1) ? t : (LENF - 1);
    for (int k = 0; k <= kmax; ++k) {
        float w = uh[k * NB + b];
        ys = fmaf(qs_ws[(t - k) * NB + b], w, ys);
        yg = fmaf(qg_ws[(t - k) * NB + b], w, yg);
    }
    float* o = out + (t * NB + b) * 6;
    o[0] = ys + yg;
    o[1] = ys;
    o[2] = yg;
}

// ===========================================================================
extern "C" void kernel_launch(void* const* d_in, const int* in_sizes, int n_in,
                              void* d_out, int out_size, void* d_ws, size_t ws_size,
                              hipStream_t stream) {
    const float* x   = (const float*)d_in[0];   // (T,B,2) fp32
    const float* raw = (const float*)d_in[1];   // (B,34)  fp32
    float* out = (float*)d_out;                 // (T,B,6) fp32

    const size_t need = (size_t)NLANES * TPAD * 2 * sizeof(float);  // 47.1 MB
    if (ws_size >= need) {
        float* snp = (float*)d_ws;
        float* gnp = snp + (size_t)NLANES * TPAD;
        scan_state<<<dim3(NLANES / 64), dim3(64),  0, stream>>>(x, raw, snp, gnp);
        finalize  <<<dim3(3, NB),       dim3(256), 0, stream>>>(x, raw, snp, gnp, out);
    } else {
        float* qs = (float*)d_ws;
        float* qg = qs + (size_t)T_STEPS * NB;
        float* uh = qg + (size_t)T_STEPS * NB;
        float* dm = uh + (size_t)LENF * NB;
        uh_fb  <<<dim3((NB + 255) / 256),          dim3(256), 0, stream>>>(raw, uh);
        scan_fb<<<dim3(NB / 8),                    dim3(64),  0, stream>>>(x, raw, out, qs, qg, dm);
        conv_fb<<<dim3((NB + 255) / 256, T_STEPS), dim3(256), 0, stream>>>(qs, qg, uh, out);
    }
}